// Round 6
// baseline (876.883 us; speedup 1.0000x reference)
//
#include <hip/hip_runtime.h>

#define HID 32
#define SH 9                 // bucket covers 512 nodes
#define BNODES 512
#define NBMAX 320            // >= ceil(150000/512)=293
#define TILE 8192            // edges per bucketize block

typedef unsigned int uint;

// ---- per-tile bucket counting: LDS hist then one global atomic per bucket ----
__global__ void k_bcount(const int* __restrict__ dst, int* __restrict__ bcnt, int E, int NB) {
    __shared__ int c[NBMAX];
    for (int b = threadIdx.x; b < NBMAX; b += blockDim.x) c[b] = 0;
    __syncthreads();
    int base = blockIdx.x * TILE;
    for (int k = 0; k < TILE / 256; ++k) {
        int i = base + k * 256 + threadIdx.x;
        if (i < E) atomicAdd(&c[dst[i] >> SH], 1);
    }
    __syncthreads();
    for (int b = threadIdx.x; b < NB; b += blockDim.x)
        if (c[b]) atomicAdd(&bcnt[b], c[b]);
}

// ---- exclusive scan of bucket counts (single block; 64-lane wave scan of 5-seg sums) ----
__global__ void k_scanb(const int* __restrict__ bcnt, int* __restrict__ bbase, int NB) {
    __shared__ int l[NBMAX + 1];
    int tid = threadIdx.x;
    if (tid < 64) {
        int lo = tid * 5;
        int s = 0;
        for (int b = lo; b < lo + 5 && b < NB; ++b) s += bcnt[b];
        int v = s;
        for (int off = 1; off < 64; off <<= 1) {
            int u = __shfl_up(v, off, 64);
            if (tid >= off) v += u;
        }
        int excl = v - s;
        for (int b = lo; b < lo + 5 && b < NB; ++b) { l[b] = excl; excl += bcnt[b]; }
        if (tid == 63) l[NB] = excl;
    }
    __syncthreads();
    for (int b = tid; b <= NB; b += blockDim.x) bbase[b] = l[b];
}

// ---- bucketize: tile -> LDS counting sort by bucket -> contiguous chunk append to ebuf ----
// packed edge word: src | (dlow << 18)   (src < 2^18, dlow < 512)
__global__ void __launch_bounds__(256) k_bucketize(
        const int* __restrict__ src, const int* __restrict__ dst,
        const int* __restrict__ bbase, int* __restrict__ bcur,
        uint* __restrict__ ebuf, int E, int NB) {
    __shared__ uint  ecache[TILE];
    __shared__ unsigned short bcache[TILE];
    __shared__ int cnt[NBMAX];       // tile-local counts, then cursor
    __shared__ int loff[NBMAX + 1];  // tile-local exclusive offsets
    __shared__ int gbase[NBMAX];     // reserved global base per bucket
    int tid = threadIdx.x;
    int tbase = blockIdx.x * TILE;
    int tcount = min(E - tbase, TILE);

    for (int b = tid; b < NBMAX; b += 256) cnt[b] = 0;
    __syncthreads();
    // phase 1: count
    for (int k = 0; k < TILE / 256; ++k) {
        int i = tbase + k * 256 + tid;
        if (i < E) atomicAdd(&cnt[dst[i] >> SH], 1);
    }
    __syncthreads();
    // phase 2: scan (wave 0)
    if (tid < 64) {
        int lo = tid * 5;
        int s = 0;
        for (int b = lo; b < lo + 5 && b < NB; ++b) s += cnt[b];
        int v = s;
        for (int off = 1; off < 64; off <<= 1) {
            int u = __shfl_up(v, off, 64);
            if (tid >= off) v += u;
        }
        int excl = v - s;
        for (int b = lo; b < lo + 5 && b < NB; ++b) { loff[b] = excl; excl += cnt[b]; }
        if (tid == 63) loff[NB] = excl;
    }
    __syncthreads();
    // cursor = loff copy
    for (int b = tid; b < NB; b += 256) cnt[b] = loff[b];
    __syncthreads();
    // phase 3: place into LDS ordered by bucket
    for (int k = 0; k < TILE / 256; ++k) {
        int i = tbase + k * 256 + tid;
        if (i < E) {
            int d = dst[i];
            int b = d >> SH;
            int pos = atomicAdd(&cnt[b], 1);
            ecache[pos] = (uint)src[i] | ((uint)(d & (BNODES - 1)) << 18);
            bcache[pos] = (unsigned short)b;
        }
    }
    __syncthreads();
    // phase 4: reserve global chunks
    for (int b = tid; b < NB; b += 256) {
        int tc = loff[b + 1] - loff[b];
        if (tc > 0) gbase[b] = bbase[b] + atomicAdd(&bcur[b], tc);
    }
    __syncthreads();
    // phase 5: contiguous write-out
    for (int j = tid; j < tcount; j += 256) {
        int b = bcache[j];
        ebuf[gbase[b] + (j - loff[b])] = ecache[j];
    }
}

// ---- per-bucket degree -> dinv ----
__global__ void k_deg(const uint* __restrict__ ebuf, const int* __restrict__ bbase,
                      const int* __restrict__ bcnt, float* __restrict__ dinv, int N) {
    __shared__ int c[BNODES];
    int b = blockIdx.x, tid = threadIdx.x;
    for (int t = tid; t < BNODES; t += 256) c[t] = 0;
    __syncthreads();
    int base = bbase[b], cnt = bcnt[b];
    for (int j = tid; j < cnt; j += 256) atomicAdd(&c[ebuf[base + j] >> 18], 1);
    __syncthreads();
    for (int t = tid; t < BNODES; t += 256) {
        int node = (b << SH) + t;
        if (node < N) dinv[node] = rsqrtf((float)c[t] + 1.0f);
    }
}

// ---- p1 = x * dinv  (N x 2) ----
__global__ void k_lin1(const float* __restrict__ x, const float* __restrict__ dinv,
                       float2* __restrict__ p1, int N) {
    int i = blockIdx.x * 256 + threadIdx.x;
    if (i < N) {
        float di = dinv[i];
        float2 v = ((const float2*)x)[i];
        p1[i] = make_float2(v.x * di, v.y * di);
    }
}

// ---- layer-1 aggregate (2-wide) + fused W1/ReLU/W2/pre-scale -> p2 ----
__global__ void __launch_bounds__(512) k_agg1(
        const uint* __restrict__ ebuf, const int* __restrict__ bbase,
        const int* __restrict__ bcnt, const float2* __restrict__ p1,
        const float* __restrict__ W1, const float* __restrict__ b1,
        const float* __restrict__ W2, const float* __restrict__ dinv,
        float* __restrict__ p2, int N) {
    __shared__ float acc[BNODES * 2];
    __shared__ float sW1[64], sb1[32], sW2[HID * HID];
    int tid = threadIdx.x, b = blockIdx.x;
    for (int t = tid; t < BNODES * 2; t += 512) { acc[t] = 0.0f; sW2[t] = W2[t]; }
    if (tid < 64) sW1[tid] = W1[tid];
    if (tid < 32) sb1[tid] = b1[tid];
    __syncthreads();
    int base = bbase[b], cnt = bcnt[b];
    for (int j = tid; j < cnt; j += 512) {
        uint e = ebuf[base + j];
        int s = e & 0x3FFFF, dl = e >> 18;
        float2 v = p1[s];
        atomicAdd(&acc[dl * 2 + 0], v.x);
        atomicAdd(&acc[dl * 2 + 1], v.y);
    }
    __syncthreads();
    int f = tid & 31;
    for (int nrel = tid >> 5; nrel < BNODES; nrel += 16) {
        int node = (b << SH) + nrel;
        if (node >= N) continue;  // uniform within 32-lane group
        float di = dinv[node];
        float2 self = p1[node];
        float g0 = di * (acc[nrel * 2 + 0] + self.x);
        float g1 = di * (acc[nrel * 2 + 1] + self.y);
        float h = fmaxf(g0 * sW1[f] + g1 * sW1[32 + f] + sb1[f], 0.0f);
        float o = 0.0f;
#pragma unroll
        for (int k = 0; k < HID; ++k)
            o += __shfl(h, k, 32) * sW2[k * HID + f];
        p2[(long)node * HID + f] = di * o;
    }
}

// ---- layer-2 aggregate into 64KB LDS + fused bias/ReLU/Wp/sigmoid -> out ----
__global__ void __launch_bounds__(1024) k_agg2(
        const uint* __restrict__ ebuf, const int* __restrict__ bbase,
        const int* __restrict__ bcnt, const float* __restrict__ p2,
        const float* __restrict__ b2, const float* __restrict__ Wp,
        const float* __restrict__ bp, const float* __restrict__ dinv,
        float* __restrict__ out, int N) {
    __shared__ float acc[BNODES * HID];  // 64 KB
    __shared__ float sb2[32], sWp[32];
    int tid = threadIdx.x, b = blockIdx.x;
    for (int t = tid; t < BNODES * HID; t += 1024) acc[t] = 0.0f;
    if (tid < 32) { sb2[tid] = b2[tid]; sWp[tid] = Wp[tid]; }
    __syncthreads();
    int base = bbase[b], cnt = bcnt[b];
    int f = tid & 31;
    for (int j = tid >> 5; j < cnt; j += 32) {
        uint e = ebuf[base + j];            // broadcast within 32-lane group
        int s = e & 0x3FFFF, dl = e >> 18;
        atomicAdd(&acc[dl * HID + f], p2[(long)s * HID + f]);  // bank = f, conflict-free
    }
    __syncthreads();
    for (int nrel = tid >> 5; nrel < BNODES; nrel += 32) {
        int node = (b << SH) + nrel;
        if (node >= N) continue;  // uniform within group
        float di = dinv[node];
        float hv = fmaxf(di * (acc[nrel * HID + f] + p2[(long)node * HID + f]) + sb2[f], 0.0f);
        float v = hv * sWp[f];
#pragma unroll
        for (int m = 16; m > 0; m >>= 1) v += __shfl_xor(v, m, 32);
        if (f == 0) out[node] = 1.0f / (1.0f + expf(-(v + bp[0])));
    }
}

extern "C" void kernel_launch(void* const* d_in, const int* in_sizes, int n_in,
                              void* d_out, int out_size, void* d_ws, size_t ws_size,
                              hipStream_t stream) {
    const float* x  = (const float*)d_in[0];
    const int*   ei = (const int*)d_in[1];
    const float* W1 = (const float*)d_in[2];
    const float* b1 = (const float*)d_in[3];
    const float* W2 = (const float*)d_in[4];
    const float* b2 = (const float*)d_in[5];
    const float* Wp = (const float*)d_in[6];
    const float* bp = (const float*)d_in[7];
    float* out = (float*)d_out;

    const int N = in_sizes[0] / 2;   // IN_DIM = 2
    const int E = in_sizes[1] / 2;   // edge_index is [2, E]
    const int* src = ei;
    const int* dst = ei + E;
    const int NB = (N + BNODES - 1) >> SH;  // 293 for N=150000 (<= NBMAX)

    // ---- workspace layout (256B aligned) ----
    char* ws = (char*)d_ws;
    size_t off = 0;
    auto alloc = [&](size_t bytes) {
        void* ptr = ws + off;
        off += (bytes + 255) & ~(size_t)255;
        return ptr;
    };
    int*    bcnt  = (int*)alloc((size_t)NBMAX * 4);
    int*    bbase = (int*)alloc((size_t)(NBMAX + 1) * 4);
    int*    bcur  = (int*)alloc((size_t)NBMAX * 4);
    float*  dinv  = (float*)alloc((size_t)N * 4);
    float2* p1    = (float2*)alloc((size_t)N * 8);
    float*  p2    = (float*)alloc((size_t)N * HID * 4);
    uint*   ebuf  = (uint*)alloc((size_t)E * 4);

    const int nb_t = (E + TILE - 1) / TILE;
    const int nb_n = (N + 255) / 256;

    hipMemsetAsync(bcnt, 0, (size_t)NBMAX * 4, stream);
    hipMemsetAsync(bcur, 0, (size_t)NBMAX * 4, stream);
    k_bcount<<<nb_t, 256, 0, stream>>>(dst, bcnt, E, NB);
    k_scanb<<<1, 256, 0, stream>>>(bcnt, bbase, NB);
    k_bucketize<<<nb_t, 256, 0, stream>>>(src, dst, bbase, bcur, ebuf, E, NB);
    k_deg<<<NB, 256, 0, stream>>>(ebuf, bbase, bcnt, dinv, N);
    k_lin1<<<nb_n, 256, 0, stream>>>(x, dinv, p1, N);
    k_agg1<<<NB, 512, 0, stream>>>(ebuf, bbase, bcnt, p1, W1, b1, W2, dinv, p2, N);
    k_agg2<<<NB, 1024, 0, stream>>>(ebuf, bbase, bcnt, p2, b2, Wp, bp, dinv, out, N);
}

// Round 7
// 267.955 us; speedup vs baseline: 3.2725x; 3.2725x over previous
//
#include <hip/hip_runtime.h>

#define HID 32
#define SH 9                 // bucket covers 512 nodes
#define BNODES 512
#define NBMAX 320            // >= ceil(150000/512)=293
#define TILE 8192            // edges per bucketize block

typedef unsigned int uint;

// ---- per-tile bucket counting: LDS hist then one global atomic per bucket ----
__global__ void k_bcount(const int* __restrict__ dst, int* __restrict__ bcnt, int E, int NB) {
    __shared__ int c[NBMAX];
    for (int b = threadIdx.x; b < NBMAX; b += blockDim.x) c[b] = 0;
    __syncthreads();
    int base = blockIdx.x * TILE;
    for (int k = 0; k < TILE / 256; ++k) {
        int i = base + k * 256 + threadIdx.x;
        if (i < E) atomicAdd(&c[dst[i] >> SH], 1);
    }
    __syncthreads();
    for (int b = threadIdx.x; b < NB; b += blockDim.x)
        if (c[b]) atomicAdd(&bcnt[b], c[b]);
}

// ---- exclusive scan of bucket counts; also writes rowptr[N] = E ----
__global__ void k_scanb(const int* __restrict__ bcnt, int* __restrict__ bbase,
                        int* __restrict__ rowptr, int N, int NB) {
    __shared__ int l[NBMAX + 1];
    int tid = threadIdx.x;
    if (tid < 64) {
        int lo = tid * 5;
        int s = 0;
        for (int b = lo; b < lo + 5 && b < NB; ++b) s += bcnt[b];
        int v = s;
        for (int off = 1; off < 64; off <<= 1) {
            int u = __shfl_up(v, off, 64);
            if (tid >= off) v += u;
        }
        int excl = v - s;
        for (int b = lo; b < lo + 5 && b < NB; ++b) { l[b] = excl; excl += bcnt[b]; }
        if (tid == 63) l[NB] = excl;
    }
    __syncthreads();
    for (int b = tid; b <= NB; b += blockDim.x) bbase[b] = l[b];
    if (tid == 0) rowptr[N] = l[NB];
}

// ---- bucketize: tile -> LDS counting sort by bucket -> contiguous chunk append to ebuf ----
// packed edge word: src | (dlow << 18)   (src < 2^18, dlow < 512)
__global__ void __launch_bounds__(256) k_bucketize(
        const int* __restrict__ src, const int* __restrict__ dst,
        const int* __restrict__ bbase, int* __restrict__ bcur,
        uint* __restrict__ ebuf, int E, int NB) {
    __shared__ uint  ecache[TILE];
    __shared__ unsigned short bcache[TILE];
    __shared__ int cnt[NBMAX];       // tile-local counts, then cursor
    __shared__ int loff[NBMAX + 1];  // tile-local exclusive offsets
    __shared__ int gbase[NBMAX];     // reserved global base per bucket
    int tid = threadIdx.x;
    int tbase = blockIdx.x * TILE;
    int tcount = min(E - tbase, TILE);

    for (int b = tid; b < NBMAX; b += 256) cnt[b] = 0;
    __syncthreads();
    // phase 1: count
    for (int k = 0; k < TILE / 256; ++k) {
        int i = tbase + k * 256 + tid;
        if (i < E) atomicAdd(&cnt[dst[i] >> SH], 1);
    }
    __syncthreads();
    // phase 2: scan (wave 0)
    if (tid < 64) {
        int lo = tid * 5;
        int s = 0;
        for (int b = lo; b < lo + 5 && b < NB; ++b) s += cnt[b];
        int v = s;
        for (int off = 1; off < 64; off <<= 1) {
            int u = __shfl_up(v, off, 64);
            if (tid >= off) v += u;
        }
        int excl = v - s;
        for (int b = lo; b < lo + 5 && b < NB; ++b) { loff[b] = excl; excl += cnt[b]; }
        if (tid == 63) loff[NB] = excl;
    }
    __syncthreads();
    // cursor = loff copy
    for (int b = tid; b < NB; b += 256) cnt[b] = loff[b];
    __syncthreads();
    // phase 3: place into LDS ordered by bucket
    for (int k = 0; k < TILE / 256; ++k) {
        int i = tbase + k * 256 + tid;
        if (i < E) {
            int d = dst[i];
            int b = d >> SH;
            int pos = atomicAdd(&cnt[b], 1);
            ecache[pos] = (uint)src[i] | ((uint)(d & (BNODES - 1)) << 18);
            bcache[pos] = (unsigned short)b;
        }
    }
    __syncthreads();
    // phase 4: reserve global chunks
    for (int b = tid; b < NB; b += 256) {
        int tc = loff[b + 1] - loff[b];
        if (tc > 0) gbase[b] = bbase[b] + atomicAdd(&bcur[b], tc);
    }
    __syncthreads();
    // phase 5: contiguous write-out
    for (int j = tid; j < tcount; j += 256) {
        int b = bcache[j];
        ebuf[gbase[b] + (j - loff[b])] = ecache[j];
    }
}

// ---- per-bucket counting sort by node: emits rowptr, dinv, dst-sorted col ----
// No edge staging in LDS (robust to any bucket size): count pass + placement pass.
__global__ void __launch_bounds__(256) k_sortb(
        const uint* __restrict__ ebuf, const int* __restrict__ bbase,
        int* __restrict__ rowptr, float* __restrict__ dinv,
        int* __restrict__ col, int N) {
    __shared__ int c[BNODES];    // per-node counts
    __shared__ int off[BNODES];  // exclusive offsets within bucket
    __shared__ int cur[BNODES];  // placement cursors
    int b = blockIdx.x, tid = threadIdx.x;
    int base = bbase[b], cnt = bbase[b + 1] - base;
    for (int t = tid; t < BNODES; t += 256) c[t] = 0;
    __syncthreads();
    for (int j = tid; j < cnt; j += 256)
        atomicAdd(&c[ebuf[base + j] >> 18], 1);
    __syncthreads();
    // scan 512 counters: 64 lanes x 8 each (wave 0)
    if (tid < 64) {
        int lo = tid * 8, s = 0;
#pragma unroll
        for (int k = 0; k < 8; ++k) s += c[lo + k];
        int v = s;
        for (int o = 1; o < 64; o <<= 1) {
            int u = __shfl_up(v, o, 64);
            if (tid >= o) v += u;
        }
        int excl = v - s;
#pragma unroll
        for (int k = 0; k < 8; ++k) { off[lo + k] = excl; excl += c[lo + k]; }
    }
    __syncthreads();
    for (int t = tid; t < BNODES; t += 256) {
        cur[t] = off[t];
        int node = (b << SH) + t;
        if (node < N) {
            rowptr[node] = base + off[t];
            dinv[node] = rsqrtf((float)c[t] + 1.0f);
        }
    }
    __syncthreads();
    for (int j = tid; j < cnt; j += 256) {
        uint e = ebuf[base + j];
        int dl = e >> 18;
        int pos = atomicAdd(&cur[dl], 1);
        col[base + pos] = (int)(e & 0x3FFFF);
    }
}

// ---- p1 = x * dinv  (N x 2) ----
__global__ void k_lin1(const float* __restrict__ x, const float* __restrict__ dinv,
                       float2* __restrict__ p1, int N) {
    int i = blockIdx.x * 256 + threadIdx.x;
    if (i < N) {
        float di = dinv[i];
        float2 v = ((const float2*)x)[i];
        p1[i] = make_float2(v.x * di, v.y * di);
    }
}

// ---- layer-1 aggregate, 2-wide pull: g[i] = p1[i] + sum_j p1[col[j]] ----
__global__ void k_gather1(const int* __restrict__ rowptr, const int* __restrict__ col,
                          const float2* __restrict__ p1, float2* __restrict__ g, int N) {
    int i = blockIdx.x * 256 + threadIdx.x;
    if (i >= N) return;
    int beg = rowptr[i], end = rowptr[i + 1];
    float2 s = p1[i];
    for (int j = beg; j < end; ++j) {
        float2 v = p1[col[j]];
        s.x += v.x;
        s.y += v.y;
    }
    g[i] = s;
}

// ---- fused W1/ReLU/W2/pre-scale: p2[i] = dinv[i] * (relu(dinv[i]*g[i] @ W1 + b1) @ W2) ----
__global__ void __launch_bounds__(256) k_lin12(
        const float2* __restrict__ g, const float* __restrict__ dinv,
        const float* __restrict__ W1, const float* __restrict__ b1,
        const float* __restrict__ W2, float* __restrict__ p2, int N) {
    __shared__ float sW1[64], sb1[32], sW2[HID * HID];
    int tid = threadIdx.x;
    for (int t = tid; t < HID * HID; t += 256) sW2[t] = W2[t];
    if (tid < 64) sW1[tid] = W1[tid];
    if (tid < 32) sb1[tid] = b1[tid];
    __syncthreads();
    int f = tid & 31;
    int node = blockIdx.x * 8 + (tid >> 5);
    if (node >= N) return;
    float di = dinv[node];
    float2 gv = g[node];
    float h = fmaxf(di * gv.x * sW1[f] + di * gv.y * sW1[32 + f] + sb1[f], 0.0f);
    float o = 0.0f;
#pragma unroll
    for (int k = 0; k < HID; ++k) o += __shfl(h, k, 32) * sW2[k * HID + f];
    p2[(long)node * HID + f] = di * o;
}

// ---- layer-2 row gather + fused bias/ReLU/Wp/sigmoid -> out ----
__global__ void k_gout(const int* __restrict__ rowptr, const int* __restrict__ col,
                       const float* __restrict__ p2, const float* __restrict__ b2,
                       const float* __restrict__ Wp, const float* __restrict__ bp,
                       const float* __restrict__ dinv, float* __restrict__ out, int N) {
    int node = blockIdx.x * 8 + (threadIdx.x >> 5);
    if (node >= N) return;
    int f = threadIdx.x & 31;
    int beg = rowptr[node], end = rowptr[node + 1];
    float s = p2[(long)node * HID + f];
    for (int j = beg; j < end; ++j) s += p2[(long)col[j] * HID + f];
    float hv = fmaxf(dinv[node] * s + b2[f], 0.0f);
    float v = hv * Wp[f];
#pragma unroll
    for (int m = 16; m > 0; m >>= 1) v += __shfl_xor(v, m, 32);
    if (f == 0) out[node] = 1.0f / (1.0f + expf(-(v + bp[0])));
}

extern "C" void kernel_launch(void* const* d_in, const int* in_sizes, int n_in,
                              void* d_out, int out_size, void* d_ws, size_t ws_size,
                              hipStream_t stream) {
    const float* x  = (const float*)d_in[0];
    const int*   ei = (const int*)d_in[1];
    const float* W1 = (const float*)d_in[2];
    const float* b1 = (const float*)d_in[3];
    const float* W2 = (const float*)d_in[4];
    const float* b2 = (const float*)d_in[5];
    const float* Wp = (const float*)d_in[6];
    const float* bp = (const float*)d_in[7];
    float* out = (float*)d_out;

    const int N = in_sizes[0] / 2;   // IN_DIM = 2
    const int E = in_sizes[1] / 2;   // edge_index is [2, E]
    const int* src = ei;
    const int* dst = ei + E;
    const int NB = (N + BNODES - 1) >> SH;  // 293 for N=150000 (<= NBMAX)

    // ---- workspace layout (256B aligned) ----
    char* ws = (char*)d_ws;
    size_t off = 0;
    auto alloc = [&](size_t bytes) {
        void* ptr = ws + off;
        off += (bytes + 255) & ~(size_t)255;
        return ptr;
    };
    int*    bcnt   = (int*)alloc((size_t)NBMAX * 4);
    int*    bbase  = (int*)alloc((size_t)(NBMAX + 1) * 4);
    int*    bcur   = (int*)alloc((size_t)NBMAX * 4);
    int*    rowptr = (int*)alloc((size_t)(N + 1) * 4);
    float*  dinv   = (float*)alloc((size_t)N * 4);
    uint*   ebuf   = (uint*)alloc((size_t)E * 4);
    int*    col    = (int*)alloc((size_t)E * 4);
    float2* p1     = (float2*)alloc((size_t)N * 8);
    float2* g      = (float2*)alloc((size_t)N * 8);
    float*  p2     = (float*)alloc((size_t)N * HID * 4);

    const int nb_t = (E + TILE - 1) / TILE;
    const int nb_n = (N + 255) / 256;
    const int nb_8 = (N + 7) / 8;

    hipMemsetAsync(bcnt, 0, (size_t)NBMAX * 4, stream);
    hipMemsetAsync(bcur, 0, (size_t)NBMAX * 4, stream);
    k_bcount<<<nb_t, 256, 0, stream>>>(dst, bcnt, E, NB);
    k_scanb<<<1, 256, 0, stream>>>(bcnt, bbase, rowptr, N, NB);
    k_bucketize<<<nb_t, 256, 0, stream>>>(src, dst, bbase, bcur, ebuf, E, NB);
    k_sortb<<<NB, 256, 0, stream>>>(ebuf, bbase, rowptr, dinv, col, N);
    k_lin1<<<nb_n, 256, 0, stream>>>(x, dinv, p1, N);
    k_gather1<<<nb_n, 256, 0, stream>>>(rowptr, col, p1, g, N);
    k_lin12<<<nb_8, 256, 0, stream>>>(g, dinv, W1, b1, W2, p2, N);
    k_gout<<<nb_8, 256, 0, stream>>>(rowptr, col, p2, b2, Wp, bp, dinv, out, N);
}

// Round 8
// 195.724 us; speedup vs baseline: 4.4802x; 1.3690x over previous
//
#include <hip/hip_runtime.h>

#define HID 32
#define SH 9                 // bucket covers 512 nodes
#define BNODES 512
#define NBMAX 320            // >= ceil(150000/512)=293
#define TILE 8192            // edges per bucketize block

typedef unsigned int uint;

// ---- per-tile bucket counting: LDS hist then one global atomic per bucket ----
__global__ void k_bcount(const int* __restrict__ dst, int* __restrict__ bcnt, int E, int NB) {
    __shared__ int c[NBMAX];
    for (int b = threadIdx.x; b < NBMAX; b += blockDim.x) c[b] = 0;
    __syncthreads();
    int base = blockIdx.x * TILE;
    for (int k = 0; k < TILE / 256; ++k) {
        int i = base + k * 256 + threadIdx.x;
        if (i < E) atomicAdd(&c[dst[i] >> SH], 1);
    }
    __syncthreads();
    for (int b = threadIdx.x; b < NB; b += blockDim.x)
        if (c[b]) atomicAdd(&bcnt[b], c[b]);
}

// ---- exclusive scan of bucket counts; also writes rowptr[N] = E ----
__global__ void k_scanb(const int* __restrict__ bcnt, int* __restrict__ bbase,
                        int* __restrict__ rowptr, int N, int NB) {
    __shared__ int l[NBMAX + 1];
    int tid = threadIdx.x;
    if (tid < 64) {
        int lo = tid * 5;
        int s = 0;
        for (int b = lo; b < lo + 5 && b < NB; ++b) s += bcnt[b];
        int v = s;
        for (int off = 1; off < 64; off <<= 1) {
            int u = __shfl_up(v, off, 64);
            if (tid >= off) v += u;
        }
        int excl = v - s;
        for (int b = lo; b < lo + 5 && b < NB; ++b) { l[b] = excl; excl += bcnt[b]; }
        if (tid == 63) l[NB] = excl;
    }
    __syncthreads();
    for (int b = tid; b <= NB; b += blockDim.x) bbase[b] = l[b];
    if (tid == 0) rowptr[N] = l[NB];
}

// ---- bucketize: tile -> LDS counting sort by bucket -> contiguous chunk append to ebuf ----
// packed edge word: src | (dlow << 18)   (src < 2^18, dlow < 512)
__global__ void __launch_bounds__(256) k_bucketize(
        const int* __restrict__ src, const int* __restrict__ dst,
        const int* __restrict__ bbase, int* __restrict__ bcur,
        uint* __restrict__ ebuf, int E, int NB) {
    __shared__ uint  ecache[TILE];
    __shared__ unsigned short bcache[TILE];
    __shared__ int cnt[NBMAX];       // tile-local counts, then cursor
    __shared__ int loff[NBMAX + 1];  // tile-local exclusive offsets
    __shared__ int gbase[NBMAX];     // reserved global base per bucket
    int tid = threadIdx.x;
    int tbase = blockIdx.x * TILE;
    int tcount = min(E - tbase, TILE);

    for (int b = tid; b < NBMAX; b += 256) cnt[b] = 0;
    __syncthreads();
    // phase 1: count
    for (int k = 0; k < TILE / 256; ++k) {
        int i = tbase + k * 256 + tid;
        if (i < E) atomicAdd(&cnt[dst[i] >> SH], 1);
    }
    __syncthreads();
    // phase 2: scan (wave 0)
    if (tid < 64) {
        int lo = tid * 5;
        int s = 0;
        for (int b = lo; b < lo + 5 && b < NB; ++b) s += cnt[b];
        int v = s;
        for (int off = 1; off < 64; off <<= 1) {
            int u = __shfl_up(v, off, 64);
            if (tid >= off) v += u;
        }
        int excl = v - s;
        for (int b = lo; b < lo + 5 && b < NB; ++b) { loff[b] = excl; excl += cnt[b]; }
        if (tid == 63) loff[NB] = excl;
    }
    __syncthreads();
    // cursor = loff copy
    for (int b = tid; b < NB; b += 256) cnt[b] = loff[b];
    __syncthreads();
    // phase 3: place into LDS ordered by bucket
    for (int k = 0; k < TILE / 256; ++k) {
        int i = tbase + k * 256 + tid;
        if (i < E) {
            int d = dst[i];
            int b = d >> SH;
            int pos = atomicAdd(&cnt[b], 1);
            ecache[pos] = (uint)src[i] | ((uint)(d & (BNODES - 1)) << 18);
            bcache[pos] = (unsigned short)b;
        }
    }
    __syncthreads();
    // phase 4: reserve global chunks
    for (int b = tid; b < NB; b += 256) {
        int tc = loff[b + 1] - loff[b];
        if (tc > 0) gbase[b] = bbase[b] + atomicAdd(&bcur[b], tc);
    }
    __syncthreads();
    // phase 5: contiguous write-out
    for (int j = tid; j < tcount; j += 256) {
        int b = bcache[j];
        ebuf[gbase[b] + (j - loff[b])] = ecache[j];
    }
}

// ---- per-bucket counting sort by node: emits rowptr, dinv, p1 = x*dinv, dst-sorted col ----
__global__ void __launch_bounds__(256) k_sortb(
        const uint* __restrict__ ebuf, const int* __restrict__ bbase,
        const float* __restrict__ x,
        int* __restrict__ rowptr, float* __restrict__ dinv,
        float2* __restrict__ p1, int* __restrict__ col, int N) {
    __shared__ int c[BNODES];    // per-node counts
    __shared__ int off[BNODES];  // exclusive offsets within bucket
    __shared__ int cur[BNODES];  // placement cursors
    int b = blockIdx.x, tid = threadIdx.x;
    int base = bbase[b], cnt = bbase[b + 1] - base;
    for (int t = tid; t < BNODES; t += 256) c[t] = 0;
    __syncthreads();
    for (int j = tid; j < cnt; j += 256)
        atomicAdd(&c[ebuf[base + j] >> 18], 1);
    __syncthreads();
    // scan 512 counters: 64 lanes x 8 each (wave 0)
    if (tid < 64) {
        int lo = tid * 8, s = 0;
#pragma unroll
        for (int k = 0; k < 8; ++k) s += c[lo + k];
        int v = s;
        for (int o = 1; o < 64; o <<= 1) {
            int u = __shfl_up(v, o, 64);
            if (tid >= o) v += u;
        }
        int excl = v - s;
#pragma unroll
        for (int k = 0; k < 8; ++k) { off[lo + k] = excl; excl += c[lo + k]; }
    }
    __syncthreads();
    for (int t = tid; t < BNODES; t += 256) {
        cur[t] = off[t];
        int node = (b << SH) + t;
        if (node < N) {
            rowptr[node] = base + off[t];
            float di = rsqrtf((float)c[t] + 1.0f);
            dinv[node] = di;
            float2 xv = ((const float2*)x)[node];
            p1[node] = make_float2(xv.x * di, xv.y * di);
        }
    }
    __syncthreads();
    for (int j = tid; j < cnt; j += 256) {
        uint e = ebuf[base + j];
        int dl = e >> 18;
        int pos = atomicAdd(&cur[dl], 1);
        col[base + pos] = (int)(e & 0x3FFFF);
    }
}

// ---- layer-1 aggregate, 2-wide pull, 4-way unrolled: g[i] = p1[i] + sum_j p1[col[j]] ----
__global__ void k_gather1(const int* __restrict__ rowptr, const int* __restrict__ col,
                          const float2* __restrict__ p1, float2* __restrict__ g, int N) {
    int i = blockIdx.x * 256 + threadIdx.x;
    if (i >= N) return;
    int beg = rowptr[i], end = rowptr[i + 1];
    float2 a = p1[i];
    float s0x = a.x, s0y = a.y, s1x = 0, s1y = 0, s2x = 0, s2y = 0, s3x = 0, s3y = 0;
    int j = beg;
    for (; j + 4 <= end; j += 4) {
        int c0 = col[j], c1 = col[j + 1], c2 = col[j + 2], c3 = col[j + 3];
        float2 v0 = p1[c0], v1 = p1[c1], v2 = p1[c2], v3 = p1[c3];
        s0x += v0.x; s0y += v0.y;
        s1x += v1.x; s1y += v1.y;
        s2x += v2.x; s2y += v2.y;
        s3x += v3.x; s3y += v3.y;
    }
    for (; j < end; ++j) {
        float2 v = p1[col[j]];
        s0x += v.x; s0y += v.y;
    }
    g[i] = make_float2((s0x + s1x) + (s2x + s3x), (s0y + s1y) + (s2y + s3y));
}

// ---- fused W1/ReLU/W2/pre-scale: p2[i] = dinv[i] * (relu(dinv[i]*g[i] @ W1 + b1) @ W2) ----
__global__ void __launch_bounds__(256) k_lin12(
        const float2* __restrict__ g, const float* __restrict__ dinv,
        const float* __restrict__ W1, const float* __restrict__ b1,
        const float* __restrict__ W2, float* __restrict__ p2, int N) {
    __shared__ float sW1[64], sb1[32], sW2[HID * HID];
    int tid = threadIdx.x;
    for (int t = tid; t < HID * HID; t += 256) sW2[t] = W2[t];
    if (tid < 64) sW1[tid] = W1[tid];
    if (tid < 32) sb1[tid] = b1[tid];
    __syncthreads();
    int f = tid & 31;
    int node = blockIdx.x * 8 + (tid >> 5);
    if (node >= N) return;
    float di = dinv[node];
    float2 gv = g[node];
    float h = fmaxf(di * gv.x * sW1[f] + di * gv.y * sW1[32 + f] + sb1[f], 0.0f);
    float o = 0.0f;
#pragma unroll
    for (int k = 0; k < HID; ++k) o += __shfl(h, k, 32) * sW2[k * HID + f];
    p2[(long)node * HID + f] = di * o;
}

// ---- layer-2 row gather (4-way unrolled) + fused bias/ReLU/Wp/sigmoid -> out ----
__global__ void k_gout(const int* __restrict__ rowptr, const int* __restrict__ col,
                       const float* __restrict__ p2, const float* __restrict__ b2,
                       const float* __restrict__ Wp, const float* __restrict__ bp,
                       const float* __restrict__ dinv, float* __restrict__ out, int N) {
    int node = blockIdx.x * 8 + (threadIdx.x >> 5);
    if (node >= N) return;
    int f = threadIdx.x & 31;
    int beg = rowptr[node], end = rowptr[node + 1];
    float s0 = p2[(long)node * HID + f], s1 = 0, s2 = 0, s3 = 0;
    int j = beg;
    for (; j + 4 <= end; j += 4) {
        int c0 = col[j], c1 = col[j + 1], c2 = col[j + 2], c3 = col[j + 3];
        s0 += p2[(long)c0 * HID + f];
        s1 += p2[(long)c1 * HID + f];
        s2 += p2[(long)c2 * HID + f];
        s3 += p2[(long)c3 * HID + f];
    }
    for (; j < end; ++j) s0 += p2[(long)col[j] * HID + f];
    float s = (s0 + s1) + (s2 + s3);
    float hv = fmaxf(dinv[node] * s + b2[f], 0.0f);
    float v = hv * Wp[f];
#pragma unroll
    for (int m = 16; m > 0; m >>= 1) v += __shfl_xor(v, m, 32);
    if (f == 0) out[node] = 1.0f / (1.0f + expf(-(v + bp[0])));
}

extern "C" void kernel_launch(void* const* d_in, const int* in_sizes, int n_in,
                              void* d_out, int out_size, void* d_ws, size_t ws_size,
                              hipStream_t stream) {
    const float* x  = (const float*)d_in[0];
    const int*   ei = (const int*)d_in[1];
    const float* W1 = (const float*)d_in[2];
    const float* b1 = (const float*)d_in[3];
    const float* W2 = (const float*)d_in[4];
    const float* b2 = (const float*)d_in[5];
    const float* Wp = (const float*)d_in[6];
    const float* bp = (const float*)d_in[7];
    float* out = (float*)d_out;

    const int N = in_sizes[0] / 2;   // IN_DIM = 2
    const int E = in_sizes[1] / 2;   // edge_index is [2, E]
    const int* src = ei;
    const int* dst = ei + E;
    const int NB = (N + BNODES - 1) >> SH;  // 293 for N=150000 (<= NBMAX)

    // ---- workspace layout (256B aligned) ----
    char* ws = (char*)d_ws;
    size_t off = 0;
    auto alloc = [&](size_t bytes) {
        void* ptr = ws + off;
        off += (bytes + 255) & ~(size_t)255;
        return ptr;
    };
    int*    bcnt   = (int*)alloc((size_t)NBMAX * 4);
    int*    bbase  = (int*)alloc((size_t)(NBMAX + 1) * 4);
    int*    bcur   = (int*)alloc((size_t)NBMAX * 4);
    int*    rowptr = (int*)alloc((size_t)(N + 1) * 4);
    float*  dinv   = (float*)alloc((size_t)N * 4);
    uint*   ebuf   = (uint*)alloc((size_t)E * 4);
    int*    col    = (int*)alloc((size_t)E * 4);
    float2* p1     = (float2*)alloc((size_t)N * 8);
    float2* g      = (float2*)alloc((size_t)N * 8);
    float*  p2     = (float*)alloc((size_t)N * HID * 4);

    const int nb_t = (E + TILE - 1) / TILE;
    const int nb_n = (N + 255) / 256;
    const int nb_8 = (N + 7) / 8;

    hipMemsetAsync(bcnt, 0, (size_t)NBMAX * 4, stream);
    hipMemsetAsync(bcur, 0, (size_t)NBMAX * 4, stream);
    k_bcount<<<nb_t, 256, 0, stream>>>(dst, bcnt, E, NB);
    k_scanb<<<1, 256, 0, stream>>>(bcnt, bbase, rowptr, N, NB);
    k_bucketize<<<nb_t, 256, 0, stream>>>(src, dst, bbase, bcur, ebuf, E, NB);
    k_sortb<<<NB, 256, 0, stream>>>(ebuf, bbase, x, rowptr, dinv, p1, col, N);
    k_gather1<<<nb_n, 256, 0, stream>>>(rowptr, col, p1, g, N);
    k_lin12<<<nb_8, 256, 0, stream>>>(g, dinv, W1, b1, W2, p2, N);
    k_gout<<<nb_8, 256, 0, stream>>>(rowptr, col, p2, b2, Wp, bp, dinv, out, N);
}

// Round 10
// 176.331 us; speedup vs baseline: 4.9729x; 1.1100x over previous
//
#include <hip/hip_runtime.h>

#define HID 32
#define SH 9                 // bucket covers 512 nodes
#define BNODES 512
#define NBMAX 320            // >= ceil(150000/512)=293
#define TILE 8192            // edges per bucketize block

typedef unsigned int uint;

__device__ __forceinline__ uint f2bf(float v) {   // RNE f32 -> bf16 bits
    uint b = __float_as_uint(v);
    return (b + 0x7fffu + ((b >> 16) & 1u)) >> 16;
}

// ---- per-tile bucket counting: LDS hist then one global atomic per bucket ----
__global__ void k_bcount(const int* __restrict__ dst, int* __restrict__ bcnt, int E, int NB) {
    __shared__ int c[NBMAX];
    for (int b = threadIdx.x; b < NBMAX; b += blockDim.x) c[b] = 0;
    __syncthreads();
    int base = blockIdx.x * TILE;
    for (int k = 0; k < TILE / 256; ++k) {
        int i = base + k * 256 + threadIdx.x;
        if (i < E) atomicAdd(&c[dst[i] >> SH], 1);
    }
    __syncthreads();
    for (int b = threadIdx.x; b < NB; b += blockDim.x)
        if (c[b]) atomicAdd(&bcnt[b], c[b]);
}

// ---- exclusive scan of bucket counts; also writes rowptr[N] = E ----
__global__ void k_scanb(const int* __restrict__ bcnt, int* __restrict__ bbase,
                        int* __restrict__ rowptr, int N, int NB) {
    __shared__ int l[NBMAX + 1];
    int tid = threadIdx.x;
    if (tid < 64) {
        int lo = tid * 5;
        int s = 0;
        for (int b = lo; b < lo + 5 && b < NB; ++b) s += bcnt[b];
        int v = s;
        for (int off = 1; off < 64; off <<= 1) {
            int u = __shfl_up(v, off, 64);
            if (tid >= off) v += u;
        }
        int excl = v - s;
        for (int b = lo; b < lo + 5 && b < NB; ++b) { l[b] = excl; excl += bcnt[b]; }
        if (tid == 63) l[NB] = excl;
    }
    __syncthreads();
    for (int b = tid; b <= NB; b += blockDim.x) bbase[b] = l[b];
    if (tid == 0) rowptr[N] = l[NB];
}

// ---- bucketize: tile -> LDS counting sort by bucket -> contiguous chunk append to ebuf ----
// packed edge word: src | (dlow << 18)   (src < 2^18, dlow < 512)
__global__ void __launch_bounds__(256) k_bucketize(
        const int* __restrict__ src, const int* __restrict__ dst,
        const int* __restrict__ bbase, int* __restrict__ bcur,
        uint* __restrict__ ebuf, int E, int NB) {
    __shared__ uint  ecache[TILE];
    __shared__ unsigned short bcache[TILE];
    __shared__ int cnt[NBMAX];       // tile-local counts, then cursor
    __shared__ int loff[NBMAX + 1];  // tile-local exclusive offsets
    __shared__ int gbase[NBMAX];     // reserved global base per bucket
    int tid = threadIdx.x;
    int tbase = blockIdx.x * TILE;
    int tcount = min(E - tbase, TILE);

    for (int b = tid; b < NBMAX; b += 256) cnt[b] = 0;
    __syncthreads();
    // phase 1: count
    for (int k = 0; k < TILE / 256; ++k) {
        int i = tbase + k * 256 + tid;
        if (i < E) atomicAdd(&cnt[dst[i] >> SH], 1);
    }
    __syncthreads();
    // phase 2: scan (wave 0)
    if (tid < 64) {
        int lo = tid * 5;
        int s = 0;
        for (int b = lo; b < lo + 5 && b < NB; ++b) s += cnt[b];
        int v = s;
        for (int off = 1; off < 64; off <<= 1) {
            int u = __shfl_up(v, off, 64);
            if (tid >= off) v += u;
        }
        int excl = v - s;
        for (int b = lo; b < lo + 5 && b < NB; ++b) { loff[b] = excl; excl += cnt[b]; }
        if (tid == 63) loff[NB] = excl;
    }
    __syncthreads();
    // cursor = loff copy
    for (int b = tid; b < NB; b += 256) cnt[b] = loff[b];
    __syncthreads();
    // phase 3: place into LDS ordered by bucket
    for (int k = 0; k < TILE / 256; ++k) {
        int i = tbase + k * 256 + tid;
        if (i < E) {
            int d = dst[i];
            int b = d >> SH;
            int pos = atomicAdd(&cnt[b], 1);
            ecache[pos] = (uint)src[i] | ((uint)(d & (BNODES - 1)) << 18);
            bcache[pos] = (unsigned short)b;
        }
    }
    __syncthreads();
    // phase 4: reserve global chunks
    for (int b = tid; b < NB; b += 256) {
        int tc = loff[b + 1] - loff[b];
        if (tc > 0) gbase[b] = bbase[b] + atomicAdd(&bcur[b], tc);
    }
    __syncthreads();
    // phase 5: contiguous write-out
    for (int j = tid; j < tcount; j += 256) {
        int b = bcache[j];
        ebuf[gbase[b] + (j - loff[b])] = ecache[j];
    }
}

// ---- per-bucket counting sort by node: emits rowptr, dinv, p1 = x*dinv, dst-sorted col ----
__global__ void __launch_bounds__(256) k_sortb(
        const uint* __restrict__ ebuf, const int* __restrict__ bbase,
        const float* __restrict__ x,
        int* __restrict__ rowptr, float* __restrict__ dinv,
        float2* __restrict__ p1, int* __restrict__ col, int N) {
    __shared__ int c[BNODES];    // per-node counts
    __shared__ int off[BNODES];  // exclusive offsets within bucket
    __shared__ int cur[BNODES];  // placement cursors
    int b = blockIdx.x, tid = threadIdx.x;
    int base = bbase[b], cnt = bbase[b + 1] - base;
    for (int t = tid; t < BNODES; t += 256) c[t] = 0;
    __syncthreads();
    for (int j = tid; j < cnt; j += 256)
        atomicAdd(&c[ebuf[base + j] >> 18], 1);
    __syncthreads();
    // scan 512 counters: 64 lanes x 8 each (wave 0)
    if (tid < 64) {
        int lo = tid * 8, s = 0;
#pragma unroll
        for (int k = 0; k < 8; ++k) s += c[lo + k];
        int v = s;
        for (int o = 1; o < 64; o <<= 1) {
            int u = __shfl_up(v, o, 64);
            if (tid >= o) v += u;
        }
        int excl = v - s;
#pragma unroll
        for (int k = 0; k < 8; ++k) { off[lo + k] = excl; excl += c[lo + k]; }
    }
    __syncthreads();
    for (int t = tid; t < BNODES; t += 256) {
        cur[t] = off[t];
        int node = (b << SH) + t;
        if (node < N) {
            rowptr[node] = base + off[t];
            float di = rsqrtf((float)c[t] + 1.0f);
            dinv[node] = di;
            float2 xv = ((const float2*)x)[node];
            p1[node] = make_float2(xv.x * di, xv.y * di);
        }
    }
    __syncthreads();
    for (int j = tid; j < cnt; j += 256) {
        uint e = ebuf[base + j];
        int dl = e >> 18;
        int pos = atomicAdd(&cur[dl], 1);
        col[base + pos] = (int)(e & 0x3FFFF);
    }
}

// ---- layer-1 aggregate, 2-wide pull, 4-way unrolled: g[i] = p1[i] + sum_j p1[col[j]] ----
__global__ void k_gather1(const int* __restrict__ rowptr, const int* __restrict__ col,
                          const float2* __restrict__ p1, float2* __restrict__ g, int N) {
    int i = blockIdx.x * 256 + threadIdx.x;
    if (i >= N) return;
    int beg = rowptr[i], end = rowptr[i + 1];
    float2 a = p1[i];
    float s0x = a.x, s0y = a.y, s1x = 0, s1y = 0, s2x = 0, s2y = 0, s3x = 0, s3y = 0;
    int j = beg;
    for (; j + 4 <= end; j += 4) {
        int c0 = col[j], c1 = col[j + 1], c2 = col[j + 2], c3 = col[j + 3];
        float2 v0 = p1[c0], v1 = p1[c1], v2 = p1[c2], v3 = p1[c3];
        s0x += v0.x; s0y += v0.y;
        s1x += v1.x; s1y += v1.y;
        s2x += v2.x; s2y += v2.y;
        s3x += v3.x; s3y += v3.y;
    }
    for (; j < end; ++j) {
        float2 v = p1[col[j]];
        s0x += v.x; s0y += v.y;
    }
    g[i] = make_float2((s0x + s1x) + (s2x + s3x), (s0y + s1y) + (s2y + s3y));
}

// ---- fused W1/ReLU/W2/pre-scale -> packed bf16 p2 rows (64B/node) ----
__global__ void __launch_bounds__(256) k_lin12(
        const float2* __restrict__ g, const float* __restrict__ dinv,
        const float* __restrict__ W1, const float* __restrict__ b1,
        const float* __restrict__ W2, uint* __restrict__ p2h, int N) {
    __shared__ float sW1[64], sb1[32], sW2[HID * HID];
    int tid = threadIdx.x;
    for (int t = tid; t < HID * HID; t += 256) sW2[t] = W2[t];
    if (tid < 64) sW1[tid] = W1[tid];
    if (tid < 32) sb1[tid] = b1[tid];
    __syncthreads();
    int f = tid & 31;
    int node = blockIdx.x * 8 + (tid >> 5);
    if (node >= N) return;
    float di = dinv[node];
    float2 gv = g[node];
    float h = fmaxf(di * gv.x * sW1[f] + di * gv.y * sW1[32 + f] + sb1[f], 0.0f);
    float o = 0.0f;
#pragma unroll
    for (int k = 0; k < HID; ++k) o += __shfl(h, k, 32) * sW2[k * HID + f];
    float po = di * o;
    float partner = __shfl_xor(po, 1, 32);   // feature f^1's value
    if (!(f & 1))
        p2h[(long)node * 16 + (f >> 1)] = f2bf(po) | (f2bf(partner) << 16);
}

// ---- layer-2 bf16 row gather: 16 lanes/node x 2 features, 4-way unrolled ----
__global__ void k_gout(const int* __restrict__ rowptr, const int* __restrict__ col,
                       const uint* __restrict__ p2h, const float* __restrict__ b2,
                       const float* __restrict__ Wp, const float* __restrict__ bp,
                       const float* __restrict__ dinv, float* __restrict__ out, int N) {
    int node = blockIdx.x * 16 + (threadIdx.x >> 4);
    if (node >= N) return;
    int hl = threadIdx.x & 15;   // owns features 2*hl, 2*hl+1
    int beg = rowptr[node], end = rowptr[node + 1];
    uint w = p2h[(long)node * 16 + hl];  // self term
    float sA0 = __uint_as_float(w << 16), sB0 = __uint_as_float(w & 0xffff0000u);
    float sA1 = 0, sB1 = 0, sA2 = 0, sB2 = 0, sA3 = 0, sB3 = 0;
    int j = beg;
    for (; j + 4 <= end; j += 4) {
        int c0 = col[j], c1 = col[j + 1], c2 = col[j + 2], c3 = col[j + 3];
        uint w0 = p2h[(long)c0 * 16 + hl];
        uint w1 = p2h[(long)c1 * 16 + hl];
        uint w2 = p2h[(long)c2 * 16 + hl];
        uint w3 = p2h[(long)c3 * 16 + hl];
        sA0 += __uint_as_float(w0 << 16); sB0 += __uint_as_float(w0 & 0xffff0000u);
        sA1 += __uint_as_float(w1 << 16); sB1 += __uint_as_float(w1 & 0xffff0000u);
        sA2 += __uint_as_float(w2 << 16); sB2 += __uint_as_float(w2 & 0xffff0000u);
        sA3 += __uint_as_float(w3 << 16); sB3 += __uint_as_float(w3 & 0xffff0000u);
    }
    for (; j < end; ++j) {
        uint wj = p2h[(long)col[j] * 16 + hl];
        sA0 += __uint_as_float(wj << 16); sB0 += __uint_as_float(wj & 0xffff0000u);
    }
    float sA = (sA0 + sA1) + (sA2 + sA3);
    float sB = (sB0 + sB1) + (sB2 + sB3);
    float di = dinv[node];
    float hvA = fmaxf(di * sA + b2[2 * hl], 0.0f);
    float hvB = fmaxf(di * sB + b2[2 * hl + 1], 0.0f);
    float v = hvA * Wp[2 * hl] + hvB * Wp[2 * hl + 1];
#pragma unroll
    for (int m = 8; m > 0; m >>= 1) v += __shfl_xor(v, m, 16);
    if (hl == 0) out[node] = 1.0f / (1.0f + expf(-(v + bp[0])));
}

extern "C" void kernel_launch(void* const* d_in, const int* in_sizes, int n_in,
                              void* d_out, int out_size, void* d_ws, size_t ws_size,
                              hipStream_t stream) {
    const float* x  = (const float*)d_in[0];
    const int*   ei = (const int*)d_in[1];
    const float* W1 = (const float*)d_in[2];
    const float* b1 = (const float*)d_in[3];
    const float* W2 = (const float*)d_in[4];
    const float* b2 = (const float*)d_in[5];
    const float* Wp = (const float*)d_in[6];
    const float* bp = (const float*)d_in[7];
    float* out = (float*)d_out;

    const int N = in_sizes[0] / 2;   // IN_DIM = 2
    const int E = in_sizes[1] / 2;   // edge_index is [2, E]
    const int* src = ei;
    const int* dst = ei + E;
    const int NB = (N + BNODES - 1) >> SH;  // 293 for N=150000 (<= NBMAX)

    // ---- workspace layout (256B aligned; bcnt+bcur adjacent for single memset) ----
    char* ws = (char*)d_ws;
    size_t off = 0;
    auto alloc = [&](size_t bytes) {
        void* ptr = ws + off;
        off += (bytes + 255) & ~(size_t)255;
        return ptr;
    };
    int*    bcnt   = (int*)alloc((size_t)NBMAX * 4);   // NBMAX*4 = 1280, 256-aligned
    int*    bcur   = (int*)alloc((size_t)NBMAX * 4);   // contiguous with bcnt
    int*    bbase  = (int*)alloc((size_t)(NBMAX + 1) * 4);
    int*    rowptr = (int*)alloc((size_t)(N + 1) * 4);
    float*  dinv   = (float*)alloc((size_t)N * 4);
    uint*   ebuf   = (uint*)alloc((size_t)E * 4);
    int*    col    = (int*)alloc((size_t)E * 4);
    float2* p1     = (float2*)alloc((size_t)N * 8);
    float2* g      = (float2*)alloc((size_t)N * 8);
    uint*   p2h    = (uint*)alloc((size_t)N * 16 * 4); // bf16 rows: 64B/node

    const int nb_t = (E + TILE - 1) / TILE;
    const int nb_n = (N + 255) / 256;
    const int nb_8 = (N + 7) / 8;
    const int nb_16 = (N + 15) / 16;

    hipMemsetAsync(bcnt, 0, (size_t)NBMAX * 8, stream);  // covers bcnt + bcur
    k_bcount<<<nb_t, 256, 0, stream>>>(dst, bcnt, E, NB);
    k_scanb<<<1, 256, 0, stream>>>(bcnt, bbase, rowptr, N, NB);
    k_bucketize<<<nb_t, 256, 0, stream>>>(src, dst, bbase, bcur, ebuf, E, NB);
    k_sortb<<<NB, 256, 0, stream>>>(ebuf, bbase, x, rowptr, dinv, p1, col, N);
    k_gather1<<<nb_n, 256, 0, stream>>>(rowptr, col, p1, g, N);
    k_lin12<<<nb_8, 256, 0, stream>>>(g, dinv, W1, b1, W2, p2h, N);
    k_gout<<<nb_16, 256, 0, stream>>>(rowptr, col, p2h, b2, Wp, bp, dinv, out, N);
}

// Round 11
// 150.708 us; speedup vs baseline: 5.8184x; 1.1700x over previous
//
#include <hip/hip_runtime.h>

#define HID 32
#define SH 9                 // bucket covers 512 nodes
#define BNODES 512
#define NBMAX 320            // >= ceil(150000/512)=293
#define TILE 8192            // edges per bucketize block

typedef unsigned int uint;

__device__ __forceinline__ uint f2bf(float v) {   // RNE f32 -> bf16 bits
    uint b = __float_as_uint(v);
    return (b + 0x7fffu + ((b >> 16) & 1u)) >> 16;
}

// ---- per-tile bucket counting: LDS hist then one global atomic per bucket ----
__global__ void k_bcount(const int* __restrict__ dst, int* __restrict__ bcnt, int E, int NB) {
    __shared__ int c[NBMAX];
    for (int b = threadIdx.x; b < NBMAX; b += blockDim.x) c[b] = 0;
    __syncthreads();
    int base = blockIdx.x * TILE;
    for (int k = 0; k < TILE / 256; ++k) {
        int i = base + k * 256 + threadIdx.x;
        if (i < E) atomicAdd(&c[dst[i] >> SH], 1);
    }
    __syncthreads();
    for (int b = threadIdx.x; b < NB; b += blockDim.x)
        if (c[b]) atomicAdd(&bcnt[b], c[b]);
}

// ---- exclusive scan of bucket counts; also writes rowptr[N] = E ----
__global__ void k_scanb(const int* __restrict__ bcnt, int* __restrict__ bbase,
                        int* __restrict__ rowptr, int N, int NB) {
    __shared__ int l[NBMAX + 1];
    int tid = threadIdx.x;
    if (tid < 64) {
        int lo = tid * 5;
        int s = 0;
        for (int b = lo; b < lo + 5 && b < NB; ++b) s += bcnt[b];
        int v = s;
        for (int off = 1; off < 64; off <<= 1) {
            int u = __shfl_up(v, off, 64);
            if (tid >= off) v += u;
        }
        int excl = v - s;
        for (int b = lo; b < lo + 5 && b < NB; ++b) { l[b] = excl; excl += bcnt[b]; }
        if (tid == 63) l[NB] = excl;
    }
    __syncthreads();
    for (int b = tid; b <= NB; b += blockDim.x) bbase[b] = l[b];
    if (tid == 0) rowptr[N] = l[NB];
}

// ---- bucketize: tile -> LDS counting sort by bucket -> contiguous chunk append to ebuf ----
// packed edge word: src | (dlow << 18)   (src < 2^18, dlow < 512)
__global__ void __launch_bounds__(256) k_bucketize(
        const int* __restrict__ src, const int* __restrict__ dst,
        const int* __restrict__ bbase, int* __restrict__ bcur,
        uint* __restrict__ ebuf, int E, int NB) {
    __shared__ uint  ecache[TILE];
    __shared__ unsigned short bcache[TILE];
    __shared__ int cnt[NBMAX];       // tile-local counts, then cursor
    __shared__ int loff[NBMAX + 1];  // tile-local exclusive offsets
    __shared__ int gbase[NBMAX];     // reserved global base per bucket
    int tid = threadIdx.x;
    int tbase = blockIdx.x * TILE;
    int tcount = min(E - tbase, TILE);

    for (int b = tid; b < NBMAX; b += 256) cnt[b] = 0;
    __syncthreads();
    // phase 1: count
    for (int k = 0; k < TILE / 256; ++k) {
        int i = tbase + k * 256 + tid;
        if (i < E) atomicAdd(&cnt[dst[i] >> SH], 1);
    }
    __syncthreads();
    // phase 2: scan (wave 0)
    if (tid < 64) {
        int lo = tid * 5;
        int s = 0;
        for (int b = lo; b < lo + 5 && b < NB; ++b) s += cnt[b];
        int v = s;
        for (int off = 1; off < 64; off <<= 1) {
            int u = __shfl_up(v, off, 64);
            if (tid >= off) v += u;
        }
        int excl = v - s;
        for (int b = lo; b < lo + 5 && b < NB; ++b) { loff[b] = excl; excl += cnt[b]; }
        if (tid == 63) loff[NB] = excl;
    }
    __syncthreads();
    // cursor = loff copy
    for (int b = tid; b < NB; b += 256) cnt[b] = loff[b];
    __syncthreads();
    // phase 3: place into LDS ordered by bucket
    for (int k = 0; k < TILE / 256; ++k) {
        int i = tbase + k * 256 + tid;
        if (i < E) {
            int d = dst[i];
            int b = d >> SH;
            int pos = atomicAdd(&cnt[b], 1);
            ecache[pos] = (uint)src[i] | ((uint)(d & (BNODES - 1)) << 18);
            bcache[pos] = (unsigned short)b;
        }
    }
    __syncthreads();
    // phase 4: reserve global chunks
    for (int b = tid; b < NB; b += 256) {
        int tc = loff[b + 1] - loff[b];
        if (tc > 0) gbase[b] = bbase[b] + atomicAdd(&bcur[b], tc);
    }
    __syncthreads();
    // phase 5: contiguous write-out
    for (int j = tid; j < tcount; j += 256) {
        int b = bcache[j];
        ebuf[gbase[b] + (j - loff[b])] = ecache[j];
    }
}

// ---- per-bucket counting sort by node: emits rowptr, dinv, p1 = x*dinv, dst-sorted col ----
__global__ void __launch_bounds__(256) k_sortb(
        const uint* __restrict__ ebuf, const int* __restrict__ bbase,
        const float* __restrict__ x,
        int* __restrict__ rowptr, float* __restrict__ dinv,
        float2* __restrict__ p1, int* __restrict__ col, int N) {
    __shared__ int c[BNODES];    // per-node counts
    __shared__ int off[BNODES];  // exclusive offsets within bucket
    __shared__ int cur[BNODES];  // placement cursors
    int b = blockIdx.x, tid = threadIdx.x;
    int base = bbase[b], cnt = bbase[b + 1] - base;
    for (int t = tid; t < BNODES; t += 256) c[t] = 0;
    __syncthreads();
    for (int j = tid; j < cnt; j += 256)
        atomicAdd(&c[ebuf[base + j] >> 18], 1);
    __syncthreads();
    // scan 512 counters: 64 lanes x 8 each (wave 0)
    if (tid < 64) {
        int lo = tid * 8, s = 0;
#pragma unroll
        for (int k = 0; k < 8; ++k) s += c[lo + k];
        int v = s;
        for (int o = 1; o < 64; o <<= 1) {
            int u = __shfl_up(v, o, 64);
            if (tid >= o) v += u;
        }
        int excl = v - s;
#pragma unroll
        for (int k = 0; k < 8; ++k) { off[lo + k] = excl; excl += c[lo + k]; }
    }
    __syncthreads();
    for (int t = tid; t < BNODES; t += 256) {
        cur[t] = off[t];
        int node = (b << SH) + t;
        if (node < N) {
            rowptr[node] = base + off[t];
            float di = rsqrtf((float)c[t] + 1.0f);
            dinv[node] = di;
            float2 xv = ((const float2*)x)[node];
            p1[node] = make_float2(xv.x * di, xv.y * di);
        }
    }
    __syncthreads();
    for (int j = tid; j < cnt; j += 256) {
        uint e = ebuf[base + j];
        int dl = e >> 18;
        int pos = atomicAdd(&cur[dl], 1);
        col[base + pos] = (int)(e & 0x3FFFF);
    }
}

// ---- FUSED layer-1 gather + W1/ReLU/W2/pre-scale -> packed bf16 p2 rows ----
// One thread per node: 2-wide gather (4-way unrolled), then register MLP with
// wave-uniform LDS broadcast reads of W2 rows (no cross-lane ops).
__global__ void __launch_bounds__(256) k_gl12(
        const int* __restrict__ rowptr, const int* __restrict__ col,
        const float2* __restrict__ p1, const float* __restrict__ dinv,
        const float* __restrict__ W1, const float* __restrict__ b1,
        const float* __restrict__ W2, uint4* __restrict__ p2h, int N) {
    __shared__ float sW1[64], sb1[32], sW2[HID * HID];
    int tid = threadIdx.x;
    for (int t = tid; t < HID * HID; t += 256) sW2[t] = W2[t];
    if (tid < 64) sW1[tid] = W1[tid];
    if (tid < 32) sb1[tid] = b1[tid];
    __syncthreads();
    int i = blockIdx.x * 256 + tid;
    if (i >= N) return;

    // gather: g = p1[i] + sum_j p1[col[j]]
    int beg = rowptr[i], end = rowptr[i + 1];
    float2 a = p1[i];
    float s0x = a.x, s0y = a.y, s1x = 0, s1y = 0, s2x = 0, s2y = 0, s3x = 0, s3y = 0;
    int j = beg;
    for (; j + 4 <= end; j += 4) {
        int c0 = col[j], c1 = col[j + 1], c2 = col[j + 2], c3 = col[j + 3];
        float2 v0 = p1[c0], v1 = p1[c1], v2 = p1[c2], v3 = p1[c3];
        s0x += v0.x; s0y += v0.y;
        s1x += v1.x; s1y += v1.y;
        s2x += v2.x; s2y += v2.y;
        s3x += v3.x; s3y += v3.y;
    }
    for (; j < end; ++j) {
        float2 v = p1[col[j]];
        s0x += v.x; s0y += v.y;
    }
    float di = dinv[i];
    float g0 = di * ((s0x + s1x) + (s2x + s3x));
    float g1 = di * ((s0y + s1y) + (s2y + s3y));

    // h = relu(g @ W1 + b1)
    float h[HID];
#pragma unroll
    for (int k = 0; k < HID; ++k)
        h[k] = fmaxf(g0 * sW1[k] + g1 * sW1[32 + k] + sb1[k], 0.0f);

    // o = h @ W2 (k ascending, same order as before)
    float o[HID];
#pragma unroll
    for (int f = 0; f < HID; ++f) o[f] = 0.0f;
#pragma unroll
    for (int k = 0; k < HID; ++k) {
        float hk = h[k];
#pragma unroll
        for (int f = 0; f < HID; ++f) o[f] += hk * sW2[k * HID + f];
    }

    // pack to bf16 pairs, store 4x uint4 (64B contiguous per node)
    long base16 = (long)i * 4;
#pragma unroll
    for (int q = 0; q < 4; ++q) {
        uint4 w;
        w.x = f2bf(di * o[8 * q + 0]) | (f2bf(di * o[8 * q + 1]) << 16);
        w.y = f2bf(di * o[8 * q + 2]) | (f2bf(di * o[8 * q + 3]) << 16);
        w.z = f2bf(di * o[8 * q + 4]) | (f2bf(di * o[8 * q + 5]) << 16);
        w.w = f2bf(di * o[8 * q + 6]) | (f2bf(di * o[8 * q + 7]) << 16);
        p2h[base16 + q] = w;
    }
}

// ---- layer-2 bf16 row gather: 16 lanes/node x 2 features, 4-way unrolled ----
__global__ void k_gout(const int* __restrict__ rowptr, const int* __restrict__ col,
                       const uint* __restrict__ p2h, const float* __restrict__ b2,
                       const float* __restrict__ Wp, const float* __restrict__ bp,
                       const float* __restrict__ dinv, float* __restrict__ out, int N) {
    int node = blockIdx.x * 16 + (threadIdx.x >> 4);
    if (node >= N) return;
    int hl = threadIdx.x & 15;   // owns features 2*hl, 2*hl+1
    int beg = rowptr[node], end = rowptr[node + 1];
    uint w = p2h[(long)node * 16 + hl];  // self term
    float sA0 = __uint_as_float(w << 16), sB0 = __uint_as_float(w & 0xffff0000u);
    float sA1 = 0, sB1 = 0, sA2 = 0, sB2 = 0, sA3 = 0, sB3 = 0;
    int j = beg;
    for (; j + 4 <= end; j += 4) {
        int c0 = col[j], c1 = col[j + 1], c2 = col[j + 2], c3 = col[j + 3];
        uint w0 = p2h[(long)c0 * 16 + hl];
        uint w1 = p2h[(long)c1 * 16 + hl];
        uint w2 = p2h[(long)c2 * 16 + hl];
        uint w3 = p2h[(long)c3 * 16 + hl];
        sA0 += __uint_as_float(w0 << 16); sB0 += __uint_as_float(w0 & 0xffff0000u);
        sA1 += __uint_as_float(w1 << 16); sB1 += __uint_as_float(w1 & 0xffff0000u);
        sA2 += __uint_as_float(w2 << 16); sB2 += __uint_as_float(w2 & 0xffff0000u);
        sA3 += __uint_as_float(w3 << 16); sB3 += __uint_as_float(w3 & 0xffff0000u);
    }
    for (; j < end; ++j) {
        uint wj = p2h[(long)col[j] * 16 + hl];
        sA0 += __uint_as_float(wj << 16); sB0 += __uint_as_float(wj & 0xffff0000u);
    }
    float sA = (sA0 + sA1) + (sA2 + sA3);
    float sB = (sB0 + sB1) + (sB2 + sB3);
    float di = dinv[node];
    float hvA = fmaxf(di * sA + b2[2 * hl], 0.0f);
    float hvB = fmaxf(di * sB + b2[2 * hl + 1], 0.0f);
    float v = hvA * Wp[2 * hl] + hvB * Wp[2 * hl + 1];
#pragma unroll
    for (int m = 8; m > 0; m >>= 1) v += __shfl_xor(v, m, 16);
    if (hl == 0) out[node] = 1.0f / (1.0f + expf(-(v + bp[0])));
}

extern "C" void kernel_launch(void* const* d_in, const int* in_sizes, int n_in,
                              void* d_out, int out_size, void* d_ws, size_t ws_size,
                              hipStream_t stream) {
    const float* x  = (const float*)d_in[0];
    const int*   ei = (const int*)d_in[1];
    const float* W1 = (const float*)d_in[2];
    const float* b1 = (const float*)d_in[3];
    const float* W2 = (const float*)d_in[4];
    const float* b2 = (const float*)d_in[5];
    const float* Wp = (const float*)d_in[6];
    const float* bp = (const float*)d_in[7];
    float* out = (float*)d_out;

    const int N = in_sizes[0] / 2;   // IN_DIM = 2
    const int E = in_sizes[1] / 2;   // edge_index is [2, E]
    const int* src = ei;
    const int* dst = ei + E;
    const int NB = (N + BNODES - 1) >> SH;  // 293 for N=150000 (<= NBMAX)

    // ---- workspace layout (256B aligned; bcnt+bcur adjacent for single memset) ----
    char* ws = (char*)d_ws;
    size_t off = 0;
    auto alloc = [&](size_t bytes) {
        void* ptr = ws + off;
        off += (bytes + 255) & ~(size_t)255;
        return ptr;
    };
    int*    bcnt   = (int*)alloc((size_t)NBMAX * 4);   // NBMAX*4 = 1280, 256-aligned
    int*    bcur   = (int*)alloc((size_t)NBMAX * 4);   // contiguous with bcnt
    int*    bbase  = (int*)alloc((size_t)(NBMAX + 1) * 4);
    int*    rowptr = (int*)alloc((size_t)(N + 1) * 4);
    float*  dinv   = (float*)alloc((size_t)N * 4);
    uint*   ebuf   = (uint*)alloc((size_t)E * 4);
    int*    col    = (int*)alloc((size_t)E * 4);
    float2* p1     = (float2*)alloc((size_t)N * 8);
    uint*   p2h    = (uint*)alloc((size_t)N * 16 * 4); // bf16 rows: 64B/node

    const int nb_t = (E + TILE - 1) / TILE;
    const int nb_n = (N + 255) / 256;
    const int nb_16 = (N + 15) / 16;

    hipMemsetAsync(bcnt, 0, (size_t)NBMAX * 8, stream);  // covers bcnt + bcur
    k_bcount<<<nb_t, 256, 0, stream>>>(dst, bcnt, E, NB);
    k_scanb<<<1, 256, 0, stream>>>(bcnt, bbase, rowptr, N, NB);
    k_bucketize<<<nb_t, 256, 0, stream>>>(src, dst, bbase, bcur, ebuf, E, NB);
    k_sortb<<<NB, 256, 0, stream>>>(ebuf, bbase, x, rowptr, dinv, p1, col, N);
    k_gl12<<<nb_n, 256, 0, stream>>>(rowptr, col, p1, dinv, W1, b1, W2, (uint4*)p2h, N);
    k_gout<<<nb_16, 256, 0, stream>>>(rowptr, col, p2h, b2, Wp, bp, dinv, out, N);
}